// Round 12
// baseline (322.510 us; speedup 1.0000x reference)
//
#include <hip/hip_runtime.h>
#include <hip/hip_bf16.h>

// x: [2, 2048, 1024] f32; mask: [2, 2048, 2048] f32; W_qkv: [1024, 3072] f32
// W_out: [1024, 1024] f32; b_out: [1024] f32; out: [2, 2048, 1024] f32
#define BATCH 2
#define SEQ   2048
#define DIM   1024
#define HEADS 16
#define DH    64
#define N_QKV 3072
#define M_TOT 4096
#define SCALE 0.125f
#define EPS   1e-10f
#define LOG2E 1.442695041f

typedef __attribute__((ext_vector_type(8))) _Float16 half8;
typedef __attribute__((ext_vector_type(4))) float f32x4;

static __device__ __forceinline__ unsigned short f2h(float f) {
    _Float16 h = (_Float16)f;
    return __builtin_bit_cast(unsigned short, h);
}
static __device__ __forceinline__ unsigned int pkrtz(float a, float b) {
#if defined(__has_builtin) && __has_builtin(__builtin_amdgcn_cvt_pkrtz)
    return __builtin_bit_cast(unsigned int, __builtin_amdgcn_cvt_pkrtz(a, b));
#else
    return (unsigned int)f2h(a) | ((unsigned int)f2h(b) << 16);
#endif
}
static __device__ __forceinline__ void glds16(const void* g, void* l) {
    __builtin_amdgcn_global_load_lds((const __attribute__((address_space(1))) void*)g,
                                     (__attribute__((address_space(3))) void*)l,
                                     16, 0, 0);
}

// ---------------------------------------------------------------------------
// Pre-pass: fp32 -> fp16
// ---------------------------------------------------------------------------
__global__ __launch_bounds__(256) void convert_f16(const float* __restrict__ s,
                                                   unsigned short* __restrict__ h) {
    const int i = blockIdx.x * 256 + threadIdx.x;
    float4 v = reinterpret_cast<const float4*>(s)[i];
    uint2 o;
    o.x = pkrtz(v.x, v.y);
    o.y = pkrtz(v.z, v.w);
    reinterpret_cast<uint2*>(h)[i] = o;
}

// ---------------------------------------------------------------------------
// Pre-pass: W [k][n] fp32 -> WT fp16 [n][k]
// ---------------------------------------------------------------------------
__global__ __launch_bounds__(256) void transpose_f16(const float* __restrict__ src,
                                                     unsigned short* __restrict__ th,
                                                     int rows, int cols) {
    __shared__ float tile[32][33];
    const int c0 = blockIdx.x * 32, r0 = blockIdx.y * 32;
    const int tx = threadIdx.x & 31, ty = threadIdx.x >> 5;
    #pragma unroll
    for (int i = ty; i < 32; i += 8)
        tile[i][tx] = src[(long)(r0 + i) * cols + c0 + tx];
    __syncthreads();
    #pragma unroll
    for (int i = ty; i < 32; i += 8)
        th[(long)(c0 + i) * rows + r0 + tx] = f2h(tile[tx][i]);
}

// ---------------------------------------------------------------------------
// Pre-pass: pack mask bits for attn v8 (key-split orientation).
// mbits[b][qblock 32][kgroup 64][lane 64] (uint32):
//   bit (kt*16 + qt*4 + r) = mask[qblock*64 + qt*16 + (lane&15)]
//                                [kgroup*32 + kt*16 + (lane>>4)*4 + r] != 0
// ---------------------------------------------------------------------------
__global__ __launch_bounds__(256) void pack_maskbits(const float* __restrict__ mask,
                                                     unsigned int* __restrict__ mbits) {
    const int qb = blockIdx.x;      // 0..31
    const int bb = blockIdx.y;
    const int t  = threadIdx.x;
    __shared__ unsigned char flags[64][256];   // 16 KB

    for (int c0 = 0; c0 < SEQ; c0 += 256) {
        #pragma unroll 4
        for (int rr = 0; rr < 64; ++rr)
            flags[rr][t] = mask[((long)bb * SEQ + qb * 64 + rr) * SEQ + c0 + t] != 0.f;
        __syncthreads();
        #pragma unroll
        for (int i = 0; i < 2; ++i) {
            const int idx = i * 256 + t;
            const int kg = idx >> 6;            // 0..7 within this 256-key chunk
            const int ln = idx & 63;
            const int lq = ln & 15, lg = ln >> 4;
            unsigned int bits = 0;
            #pragma unroll
            for (int kt = 0; kt < 2; ++kt)
                #pragma unroll
                for (int qt = 0; qt < 4; ++qt)
                    #pragma unroll
                    for (int r = 0; r < 4; ++r)
                        bits |= (unsigned int)
                                flags[qt * 16 + lq][kg * 32 + kt * 16 + lg * 4 + r]
                                << (kt * 16 + qt * 4 + r);
            mbits[(((long)bb * 32 + qb) * 64 + (c0 >> 5) + kg) * 64 + ln] = bits;
        }
        __syncthreads();
    }
}

// ---------------------------------------------------------------------------
// GEMM 1: plain fp16 MFMA, 128x128, BK=64, XOR-swizzled LDS (r11 verified).
// ---------------------------------------------------------------------------
__global__ __launch_bounds__(256) void gemm_qkv_f16(
    const unsigned short* __restrict__ Ahg, const unsigned short* __restrict__ Bhg,
    unsigned short* __restrict__ qb, unsigned short* __restrict__ kb,
    unsigned short* __restrict__ vtb) {
    __shared__ __align__(16) unsigned short As[128 * 64];
    __shared__ __align__(16) unsigned short Bs[128 * 64];

    const int n0   = blockIdx.x * 128;
    const int m0   = blockIdx.y * 128;
    const int wave = threadIdx.x >> 6;
    const int lane = threadIdx.x & 63;
    const int l16  = lane & 15;
    const int g    = lane >> 4;
    const int wm   = wave & 1;
    const int wn   = wave >> 1;
    const int sw   = l16 & 7;

    const int sr8 = lane >> 3;
    const int scg = (lane & 7) ^ sr8;

    f32x4 acc[4][4] = {};

    for (int k0 = 0; k0 < DIM; k0 += 64) {
        #pragma unroll
        for (int i = 0; i < 4; ++i) {
            const int row = wave * 32 + i * 8;
            glds16(Ahg + (long)(m0 + row + sr8) * DIM + k0 + scg * 8, &As[row * 64]);
            glds16(Bhg + (long)(n0 + row + sr8) * DIM + k0 + scg * 8, &Bs[row * 64]);
        }
        __syncthreads();

        half8 a[4][2];
        #pragma unroll
        for (int mt = 0; mt < 4; ++mt) {
            const int rbase = (wm * 64 + mt * 16 + l16) * 64;
            #pragma unroll
            for (int kc = 0; kc < 2; ++kc)
                a[mt][kc] = *reinterpret_cast<const half8*>(
                    &As[rbase + (((kc * 4 + g) ^ sw) * 8)]);
        }
        #pragma unroll
        for (int nt = 0; nt < 4; ++nt) {
            const int rbase = (wn * 64 + nt * 16 + l16) * 64;
            const half8 b0 = *reinterpret_cast<const half8*>(&Bs[rbase + (((0 + g) ^ sw) * 8)]);
            const half8 b1 = *reinterpret_cast<const half8*>(&Bs[rbase + (((4 + g) ^ sw) * 8)]);
            #pragma unroll
            for (int mt = 0; mt < 4; ++mt) {
                acc[mt][nt] = __builtin_amdgcn_mfma_f32_16x16x32_f16(a[mt][0], b0, acc[mt][nt], 0, 0, 0);
                acc[mt][nt] = __builtin_amdgcn_mfma_f32_16x16x32_f16(a[mt][1], b1, acc[mt][nt], 0, 0, 0);
            }
        }
        __syncthreads();
    }

    #pragma unroll
    for (int nt = 0; nt < 4; ++nt) {
        const int n     = n0 + wn * 64 + nt * 16 + l16;
        const int which = n >> 10;
        const int rem   = n & 1023;
        const int head  = rem >> 6;
        const int d     = rem & 63;
        #pragma unroll
        for (int mt = 0; mt < 4; ++mt) {
            #pragma unroll
            for (int r = 0; r < 4; ++r) {
                const int m  = m0 + wm * 64 + mt * 16 + g * 4 + r;
                const int bb = m >> 11;
                const int li = m & 2047;
                const int bh_i = bb * HEADS + head;
                const float val = acc[mt][nt][r];
                if (which == 0)
                    qb[((long)bh_i * SEQ + li) * DH + d] = f2h(val * SCALE);
                else if (which == 1)
                    kb[((long)bh_i * SEQ + li) * DH + d] = f2h(val);
                else
                    vtb[((long)bh_i * DH + d) * SEQ + li] = f2h(val);
            }
        }
    }
}

// ---------------------------------------------------------------------------
// GEMM 2: plain fp16 MFMA, 128x64 tiles, BK=64, XOR-swizzled (r11 verified).
// ---------------------------------------------------------------------------
__global__ __launch_bounds__(256) void gemm_out_f16(
    const unsigned short* __restrict__ Ahg, const unsigned short* __restrict__ Bhg,
    const float* __restrict__ bias, float* __restrict__ out) {
    __shared__ __align__(16) unsigned short As[128 * 64];
    __shared__ __align__(16) unsigned short Bs[64 * 64];

    const int n0   = blockIdx.x * 64;
    const int m0   = blockIdx.y * 128;
    const int wave = threadIdx.x >> 6;
    const int lane = threadIdx.x & 63;
    const int l16  = lane & 15;
    const int g    = lane >> 4;
    const int sw   = l16 & 7;

    const int sr8 = lane >> 3;
    const int scg = (lane & 7) ^ sr8;

    f32x4 acc[2][4] = {};

    for (int k0 = 0; k0 < DIM; k0 += 64) {
        #pragma unroll
        for (int i = 0; i < 4; ++i) {
            const int row = wave * 32 + i * 8;
            glds16(Ahg + (long)(m0 + row + sr8) * DIM + k0 + scg * 8, &As[row * 64]);
        }
        #pragma unroll
        for (int i = 0; i < 2; ++i) {
            const int row = wave * 16 + i * 8;
            glds16(Bhg + (long)(n0 + row + sr8) * DIM + k0 + scg * 8, &Bs[row * 64]);
        }
        __syncthreads();

        half8 a[2][2];
        #pragma unroll
        for (int mt = 0; mt < 2; ++mt) {
            const int rbase = (wave * 32 + mt * 16 + l16) * 64;
            #pragma unroll
            for (int kc = 0; kc < 2; ++kc)
                a[mt][kc] = *reinterpret_cast<const half8*>(
                    &As[rbase + (((kc * 4 + g) ^ sw) * 8)]);
        }
        #pragma unroll
        for (int nt = 0; nt < 4; ++nt) {
            const int rbase = (nt * 16 + l16) * 64;
            const half8 b0 = *reinterpret_cast<const half8*>(&Bs[rbase + (((0 + g) ^ sw) * 8)]);
            const half8 b1 = *reinterpret_cast<const half8*>(&Bs[rbase + (((4 + g) ^ sw) * 8)]);
            #pragma unroll
            for (int mt = 0; mt < 2; ++mt) {
                acc[mt][nt] = __builtin_amdgcn_mfma_f32_16x16x32_f16(a[mt][0], b0, acc[mt][nt], 0, 0, 0);
                acc[mt][nt] = __builtin_amdgcn_mfma_f32_16x16x32_f16(a[mt][1], b1, acc[mt][nt], 0, 0, 0);
            }
        }
        __syncthreads();
    }

    #pragma unroll
    for (int nt = 0; nt < 4; ++nt) {
        const int n  = n0 + nt * 16 + l16;
        const float bv = bias[n];
        #pragma unroll
        for (int mt = 0; mt < 2; ++mt) {
            #pragma unroll
            for (int r = 0; r < 4; ++r) {
                const int m = m0 + wave * 32 + mt * 16 + g * 4 + r;
                out[(long)m * DIM + n] = acc[mt][nt][r] + bv;
            }
        }
    }
}

// ---------------------------------------------------------------------------
// MFMA flash attention v8: KEY-SPLIT waves. Block = 4 waves, 64 queries;
// wave w owns keys [w*512, w*512+512), iterating 32 keys at a time.
// All LDS buffers are wave-private (K 4KB | V 4KB | P 4KB per wave) ->
// NO barriers in the main loop; per-wave s_waitcnt vmcnt(0) after glds.
// Each K/V/P element is read exactly once per block (no cross-wave
// redundancy; LDS traffic halved vs v7). Fixed-shift softmax C0=4 keeps
// j-partials linear; epilogue = one LDS exchange (wave w keeps d-tile w).
// ---------------------------------------------------------------------------
__global__ __launch_bounds__(256, 3) void attn_mfma(
    const unsigned short* __restrict__ qb, const unsigned short* __restrict__ kb,
    const unsigned short* __restrict__ vtb, const unsigned int* __restrict__ mbits,
    unsigned short* __restrict__ zz) {
    const int qblk = blockIdx.x;            // 0..31 (64-query tiles)
    const int h    = blockIdx.y;
    const int bb   = blockIdx.z;
    const int bh   = bb * HEADS + h;
    const int wave = threadIdx.x >> 6;      // j-split: wave w -> keys w*512..
    const int lane = threadIdx.x & 63;
    const int l16  = lane & 15;
    const int g    = lane >> 4;
    const int q0r  = qblk * 64;

    __shared__ __align__(16) unsigned short SMEM[4][6144]; // /wave: K 2048|V 2048|P 2048
    __shared__ float Zs[4][4][16];

    unsigned short* myK = &SMEM[wave][0];
    unsigned short* myV = &SMEM[wave][2048];
    unsigned short* myP = &SMEM[wave][4096];

    const int sw8 = l16 & 7;                // K read swizzle (8 chunks/row)
    const int swv = (l16 >> 1) & 3;         // V read swizzle (4 chunks/row)
    const int skr = lane >> 3;              // K staging: row within 8
    const int skc = ((lane & 7) ^ skr) * 8; // K staging: swizzled chunk (halves)
    const int svr = lane >> 2;              // V staging: row within 16
    const int svc = ((lane & 3) ^ ((svr >> 1) & 3)) * 8;

    // Q B-fragments: all 64 queries, d-halves 0/1 (32 VGPRs, shared workload)
    half8 qf[4][2];
    #pragma unroll
    for (int qt = 0; qt < 4; ++qt) {
        const unsigned short* qp = qb + ((long)bh * SEQ + q0r + qt * 16 + l16) * DH + g * 8;
        qf[qt][0] = *reinterpret_cast<const half8*>(qp);
        qf[qt][1] = *reinterpret_cast<const half8*>(qp + 32);
    }

    f32x4 o[4][4] = {};                     // [d-tile][q-tile]
    float Zq[4] = {0.f, 0.f, 0.f, 0.f};
    const float C0 = 4.0f * LOG2E;

    const unsigned int* mb = mbits + (((long)bb * 32 + qblk) * 64 + wave * 16) * 64 + lane;
    const long kbase = (long)bh * SEQ * DH;
    const long vbase = (long)bh * DH * SEQ;
    const int  jb    = wave * 512;

    for (int it = 0; it < 16; ++it) {
        const int j0 = jb + it * 32;
        const unsigned int bits = mb[it * 64];

        #pragma unroll
        for (int i = 0; i < 4; ++i)
            glds16(kb + kbase + (long)(j0 + i * 8 + skr) * DH + skc, myK + i * 512);
        #pragma unroll
        for (int i = 0; i < 4; ++i)
            glds16(vtb + vbase + (long)(i * 16 + svr) * SEQ + j0 + svc, myV + i * 512);
        __builtin_amdgcn_s_waitcnt(0x0F70);  // vmcnt(0): my glds landed (no barrier)

        // ---- S^T = K Q^T, kt-blocked; exp + mask + pack P ----
        #pragma unroll
        for (int kt = 0; kt < 2; ++kt) {
            const int rb = (kt * 16 + l16) * 64;
            const half8 k0 = *reinterpret_cast<const half8*>(&myK[rb + ((g ^ sw8) * 8)]);
            const half8 k1 = *reinterpret_cast<const half8*>(&myK[rb + (((4 + g) ^ sw8) * 8)]);
            f32x4 st[4];
            #pragma unroll
            for (int qt = 0; qt < 4; ++qt) {
                f32x4 acc = {0.f, 0.f, 0.f, 0.f};
                acc = __builtin_amdgcn_mfma_f32_16x16x32_f16(k0, qf[qt][0], acc, 0, 0, 0);
                acc = __builtin_amdgcn_mfma_f32_16x16x32_f16(k1, qf[qt][1], acc, 0, 0, 0);
                st[qt] = acc;
            }
            #pragma unroll
            for (int qt = 0; qt < 4; ++qt) {
                float pm[4];
                #pragma unroll
                for (int r = 0; r < 4; ++r) {
                    const float p = __builtin_amdgcn_exp2f(fmaf(st[qt][r], LOG2E, -C0));
                    pm[r] = ((bits >> (kt * 16 + qt * 4 + r)) & 1u) ? p : 0.f;
                }
                Zq[qt] += (pm[0] + pm[1]) + (pm[2] + pm[3]);
                uint2 pk2;
                pk2.x = pkrtz(pm[0], pm[1]);
                pk2.y = pkrtz(pm[2], pm[3]);
                *reinterpret_cast<uint2*>(&myP[(qt * 16 + l16) * 32 + kt * 16 + g * 4]) = pk2;
            }
        }

        // ---- O^T += V^T P^T (K=32), all 16 tiles ----
        half8 va[4];
        #pragma unroll
        for (int dt = 0; dt < 4; ++dt)
            va[dt] = *reinterpret_cast<const half8*>(&myV[(dt * 16 + l16) * 32 + ((g ^ swv) * 8)]);
        #pragma unroll
        for (int qt = 0; qt < 4; ++qt) {
            const half8 pbq = *reinterpret_cast<const half8*>(&myP[(qt * 16 + l16) * 32 + g * 8]);
            #pragma unroll
            for (int dt = 0; dt < 4; ++dt)
                o[dt][qt] = __builtin_amdgcn_mfma_f32_16x16x32_f16(va[dt], pbq, o[dt][qt], 0, 0, 0);
        }
    }

    // ---- Z: reduce over g-lanes (keys within wave) ----
    #pragma unroll
    for (int qt = 0; qt < 4; ++qt) {
        Zq[qt] += __shfl_xor(Zq[qt], 16, 64);
        Zq[qt] += __shfl_xor(Zq[qt], 32, 64);
    }

    // ---- exchange partials: wave w keeps d-tile w, swaps the other 12 ----
    __syncthreads();
    float* lx = (float*)&SMEM[0][0];        // 48 KB, reused
    #pragma unroll
    for (int dt = 0; dt < 4; ++dt) {
        if (dt == wave) continue;
        const int up = (wave < dt) ? wave : wave - 1;
        #pragma unroll
        for (int qt = 0; qt < 4; ++qt)
            *reinterpret_cast<f32x4*>(&lx[((dt * 3 + up) * 4 + qt) * 256 + lane * 4]) = o[dt][qt];
    }
    if (g == 0) {
        #pragma unroll
        for (int qt = 0; qt < 4; ++qt) Zs[wave][qt][l16] = Zq[qt];
    }
    __syncthreads();

    const int dto = wave;                   // this wave's output d-tile
    #pragma unroll
    for (int qt = 0; qt < 4; ++qt) {
        const float Zt = Zs[0][qt][l16] + Zs[1][qt][l16] + Zs[2][qt][l16] + Zs[3][qt][l16];
        const float inv = 1.f / (Zt + 1e-30f);
        f32x4 acc = o[dto][qt];
        #pragma unroll
        for (int up = 0; up < 3; ++up) {
            const f32x4 p = *reinterpret_cast<const f32x4*>(
                &lx[((dto * 3 + up) * 4 + qt) * 256 + lane * 4]);
            acc[0] += p[0]; acc[1] += p[1]; acc[2] += p[2]; acc[3] += p[3];
        }
        uint2 pk2;
        pk2.x = pkrtz(acc[0] * inv, acc[1] * inv);
        pk2.y = pkrtz(acc[2] * inv, acc[3] * inv);
        const long addr = ((long)bb * SEQ + q0r + qt * 16 + l16) * DIM + h * DH + dto * 16 + g * 4;
        *reinterpret_cast<uint2*>(&zz[addr]) = pk2;
    }
}

// ---------------------------------------------------------------------------
extern "C" void kernel_launch(void* const* d_in, const int* in_sizes, int n_in,
                              void* d_out, int out_size, void* d_ws, size_t ws_size,
                              hipStream_t stream) {
    const float* x     = (const float*)d_in[0];
    const float* mask  = (const float*)d_in[1];
    const float* W_qkv = (const float*)d_in[2];
    const float* W_out = (const float*)d_in[3];
    const float* b_out = (const float*)d_in[4];
    float* out = (float*)d_out;

    unsigned short* ws = (unsigned short*)d_ws;
    unsigned short* xh  = ws;                  // 4M fp16 (reused as z after gemm1)
    unsigned short* WqT = xh  + 4194304;       // 3M fp16
    unsigned short* WoT = WqT + 3145728;       // 1M fp16
    unsigned short* qbu = WoT + 1048576;       // 4M fp16
    unsigned short* kbu = qbu + 4194304;       // 4M fp16
    unsigned short* vtb = kbu + 4194304;       // 4M fp16
    unsigned int*   mbits = (unsigned int*)(vtb + 4194304);  // 256K uints = 1 MB
    unsigned short* zz  = xh;

    convert_f16<<<4096, 256, 0, stream>>>(x, xh);
    transpose_f16<<<dim3(96, 32), 256, 0, stream>>>(W_qkv, WqT, 1024, 3072);
    transpose_f16<<<dim3(32, 32), 256, 0, stream>>>(W_out, WoT, 1024, 1024);
    pack_maskbits<<<dim3(32, 2), 256, 0, stream>>>(mask, mbits);

    gemm_qkv_f16<<<dim3(24, 32), 256, 0, stream>>>(xh, WqT, qbu, kbu, vtb);

    attn_mfma<<<dim3(SEQ / 64, HEADS, BATCH), 256, 0, stream>>>(qbu, kbu, vtb, mbits, zz);

    gemm_out_f16<<<dim3(16, 32), 256, 0, stream>>>(zz, WoT, b_out, out);
}

// Round 13
// 290.720 us; speedup vs baseline: 1.1093x; 1.1093x over previous
//
#include <hip/hip_runtime.h>
#include <hip/hip_bf16.h>

// x: [2, 2048, 1024] f32; mask: [2, 2048, 2048] f32; W_qkv: [1024, 3072] f32
// W_out: [1024, 1024] f32; b_out: [1024] f32; out: [2, 2048, 1024] f32
#define BATCH 2
#define SEQ   2048
#define DIM   1024
#define HEADS 16
#define DH    64
#define N_QKV 3072
#define M_TOT 4096
#define SCALE 0.125f
#define EPS   1e-10f
#define LOG2E 1.442695041f

typedef __attribute__((ext_vector_type(8))) _Float16 half8;
typedef __attribute__((ext_vector_type(4))) float f32x4;

static __device__ __forceinline__ unsigned short f2h(float f) {
    _Float16 h = (_Float16)f;
    return __builtin_bit_cast(unsigned short, h);
}
static __device__ __forceinline__ unsigned int pkrtz(float a, float b) {
#if defined(__has_builtin) && __has_builtin(__builtin_amdgcn_cvt_pkrtz)
    return __builtin_bit_cast(unsigned int, __builtin_amdgcn_cvt_pkrtz(a, b));
#else
    return (unsigned int)f2h(a) | ((unsigned int)f2h(b) << 16);
#endif
}
static __device__ __forceinline__ void glds16(const void* g, void* l) {
    __builtin_amdgcn_global_load_lds((const __attribute__((address_space(1))) void*)g,
                                     (__attribute__((address_space(3))) void*)l,
                                     16, 0, 0);
}

// ---------------------------------------------------------------------------
// Pre-pass: fp32 -> fp16
// ---------------------------------------------------------------------------
__global__ __launch_bounds__(256) void convert_f16(const float* __restrict__ s,
                                                   unsigned short* __restrict__ h) {
    const int i = blockIdx.x * 256 + threadIdx.x;
    float4 v = reinterpret_cast<const float4*>(s)[i];
    uint2 o;
    o.x = pkrtz(v.x, v.y);
    o.y = pkrtz(v.z, v.w);
    reinterpret_cast<uint2*>(h)[i] = o;
}

// ---------------------------------------------------------------------------
// Pre-pass: W [k][n] fp32 -> WT fp16 [n][k]
// ---------------------------------------------------------------------------
__global__ __launch_bounds__(256) void transpose_f16(const float* __restrict__ src,
                                                     unsigned short* __restrict__ th,
                                                     int rows, int cols) {
    __shared__ float tile[32][33];
    const int c0 = blockIdx.x * 32, r0 = blockIdx.y * 32;
    const int tx = threadIdx.x & 31, ty = threadIdx.x >> 5;
    #pragma unroll
    for (int i = ty; i < 32; i += 8)
        tile[i][tx] = src[(long)(r0 + i) * cols + c0 + tx];
    __syncthreads();
    #pragma unroll
    for (int i = ty; i < 32; i += 8)
        th[(long)(c0 + i) * rows + r0 + tx] = f2h(tile[tx][i]);
}

// ---------------------------------------------------------------------------
// Pre-pass: pack mask bits, key-split orientation (r12 verified layout):
// mbits[b][qblock 32][kgroup 64][lane 64] (uint32):
//   bit (kt*16 + qt*4 + r) = mask[qblock*64 + qt*16 + (lane&15)]
//                                [kgroup*32 + kt*16 + (lane>>4)*4 + r] != 0
// ---------------------------------------------------------------------------
__global__ __launch_bounds__(256) void pack_maskbits(const float* __restrict__ mask,
                                                     unsigned int* __restrict__ mbits) {
    const int qb = blockIdx.x;      // 0..31
    const int bb = blockIdx.y;
    const int t  = threadIdx.x;
    __shared__ unsigned char flags[64][256];   // 16 KB

    for (int c0 = 0; c0 < SEQ; c0 += 256) {
        #pragma unroll 4
        for (int rr = 0; rr < 64; ++rr)
            flags[rr][t] = mask[((long)bb * SEQ + qb * 64 + rr) * SEQ + c0 + t] != 0.f;
        __syncthreads();
        #pragma unroll
        for (int i = 0; i < 2; ++i) {
            const int idx = i * 256 + t;
            const int kg = idx >> 6;            // 0..7 within this 256-key chunk
            const int ln = idx & 63;
            const int lq = ln & 15, lg = ln >> 4;
            unsigned int bits = 0;
            #pragma unroll
            for (int kt = 0; kt < 2; ++kt)
                #pragma unroll
                for (int qt = 0; qt < 4; ++qt)
                    #pragma unroll
                    for (int r = 0; r < 4; ++r)
                        bits |= (unsigned int)
                                flags[qt * 16 + lq][kg * 32 + kt * 16 + lg * 4 + r]
                                << (kt * 16 + qt * 4 + r);
            mbits[(((long)bb * 32 + qb) * 64 + (c0 >> 5) + kg) * 64 + ln] = bits;
        }
        __syncthreads();
    }
}

// ---------------------------------------------------------------------------
// GEMM 1: plain fp16 MFMA, 128x128, BK=64, XOR-swizzled LDS (r11 verified).
// ---------------------------------------------------------------------------
__global__ __launch_bounds__(256) void gemm_qkv_f16(
    const unsigned short* __restrict__ Ahg, const unsigned short* __restrict__ Bhg,
    unsigned short* __restrict__ qb, unsigned short* __restrict__ kb,
    unsigned short* __restrict__ vtb) {
    __shared__ __align__(16) unsigned short As[128 * 64];
    __shared__ __align__(16) unsigned short Bs[128 * 64];

    const int n0   = blockIdx.x * 128;
    const int m0   = blockIdx.y * 128;
    const int wave = threadIdx.x >> 6;
    const int lane = threadIdx.x & 63;
    const int l16  = lane & 15;
    const int g    = lane >> 4;
    const int wm   = wave & 1;
    const int wn   = wave >> 1;
    const int sw   = l16 & 7;

    const int sr8 = lane >> 3;
    const int scg = (lane & 7) ^ sr8;

    f32x4 acc[4][4] = {};

    for (int k0 = 0; k0 < DIM; k0 += 64) {
        #pragma unroll
        for (int i = 0; i < 4; ++i) {
            const int row = wave * 32 + i * 8;
            glds16(Ahg + (long)(m0 + row + sr8) * DIM + k0 + scg * 8, &As[row * 64]);
            glds16(Bhg + (long)(n0 + row + sr8) * DIM + k0 + scg * 8, &Bs[row * 64]);
        }
        __syncthreads();

        half8 a[4][2];
        #pragma unroll
        for (int mt = 0; mt < 4; ++mt) {
            const int rbase = (wm * 64 + mt * 16 + l16) * 64;
            #pragma unroll
            for (int kc = 0; kc < 2; ++kc)
                a[mt][kc] = *reinterpret_cast<const half8*>(
                    &As[rbase + (((kc * 4 + g) ^ sw) * 8)]);
        }
        #pragma unroll
        for (int nt = 0; nt < 4; ++nt) {
            const int rbase = (wn * 64 + nt * 16 + l16) * 64;
            const half8 b0 = *reinterpret_cast<const half8*>(&Bs[rbase + (((0 + g) ^ sw) * 8)]);
            const half8 b1 = *reinterpret_cast<const half8*>(&Bs[rbase + (((4 + g) ^ sw) * 8)]);
            #pragma unroll
            for (int mt = 0; mt < 4; ++mt) {
                acc[mt][nt] = __builtin_amdgcn_mfma_f32_16x16x32_f16(a[mt][0], b0, acc[mt][nt], 0, 0, 0);
                acc[mt][nt] = __builtin_amdgcn_mfma_f32_16x16x32_f16(a[mt][1], b1, acc[mt][nt], 0, 0, 0);
            }
        }
        __syncthreads();
    }

    #pragma unroll
    for (int nt = 0; nt < 4; ++nt) {
        const int n     = n0 + wn * 64 + nt * 16 + l16;
        const int which = n >> 10;
        const int rem   = n & 1023;
        const int head  = rem >> 6;
        const int d     = rem & 63;
        #pragma unroll
        for (int mt = 0; mt < 4; ++mt) {
            #pragma unroll
            for (int r = 0; r < 4; ++r) {
                const int m  = m0 + wm * 64 + mt * 16 + g * 4 + r;
                const int bb = m >> 11;
                const int li = m & 2047;
                const int bh_i = bb * HEADS + head;
                const float val = acc[mt][nt][r];
                if (which == 0)
                    qb[((long)bh_i * SEQ + li) * DH + d] = f2h(val * SCALE);
                else if (which == 1)
                    kb[((long)bh_i * SEQ + li) * DH + d] = f2h(val);
                else
                    vtb[((long)bh_i * DH + d) * SEQ + li] = f2h(val);
            }
        }
    }
}

// ---------------------------------------------------------------------------
// GEMM 2: plain fp16 MFMA, 128x64 tiles, BK=64, XOR-swizzled (r11 verified).
// ---------------------------------------------------------------------------
__global__ __launch_bounds__(256) void gemm_out_f16(
    const unsigned short* __restrict__ Ahg, const unsigned short* __restrict__ Bhg,
    const float* __restrict__ bias, float* __restrict__ out) {
    __shared__ __align__(16) unsigned short As[128 * 64];
    __shared__ __align__(16) unsigned short Bs[64 * 64];

    const int n0   = blockIdx.x * 64;
    const int m0   = blockIdx.y * 128;
    const int wave = threadIdx.x >> 6;
    const int lane = threadIdx.x & 63;
    const int l16  = lane & 15;
    const int g    = lane >> 4;
    const int sw   = l16 & 7;

    const int sr8 = lane >> 3;
    const int scg = (lane & 7) ^ sr8;

    f32x4 acc[2][4] = {};

    for (int k0 = 0; k0 < DIM; k0 += 64) {
        #pragma unroll
        for (int i = 0; i < 4; ++i) {
            const int row = wave * 32 + i * 8;
            glds16(Ahg + (long)(m0 + row + sr8) * DIM + k0 + scg * 8, &As[row * 64]);
        }
        #pragma unroll
        for (int i = 0; i < 2; ++i) {
            const int row = wave * 16 + i * 8;
            glds16(Bhg + (long)(n0 + row + sr8) * DIM + k0 + scg * 8, &Bs[row * 64]);
        }
        __syncthreads();

        half8 a[2][2];
        #pragma unroll
        for (int mt = 0; mt < 2; ++mt) {
            const int rbase = (wave * 32 + mt * 16 + l16) * 64;
            #pragma unroll
            for (int kc = 0; kc < 2; ++kc)
                a[mt][kc] = *reinterpret_cast<const half8*>(
                    &As[rbase + (((kc * 4 + g) ^ sw) * 8)]);
        }
        #pragma unroll
        for (int nt = 0; nt < 4; ++nt) {
            const int rbase = (nt * 16 + l16) * 64;
            const half8 b0 = *reinterpret_cast<const half8*>(&Bs[rbase + (((0 + g) ^ sw) * 8)]);
            const half8 b1 = *reinterpret_cast<const half8*>(&Bs[rbase + (((4 + g) ^ sw) * 8)]);
            #pragma unroll
            for (int mt = 0; mt < 2; ++mt) {
                acc[mt][nt] = __builtin_amdgcn_mfma_f32_16x16x32_f16(a[mt][0], b0, acc[mt][nt], 0, 0, 0);
                acc[mt][nt] = __builtin_amdgcn_mfma_f32_16x16x32_f16(a[mt][1], b1, acc[mt][nt], 0, 0, 0);
            }
        }
        __syncthreads();
    }

    #pragma unroll
    for (int nt = 0; nt < 4; ++nt) {
        const int n  = n0 + nt * 16 + l16;
        const float bv = bias[n];
        #pragma unroll
        for (int mt = 0; mt < 2; ++mt) {
            #pragma unroll
            for (int r = 0; r < 4; ++r) {
                const int m = m0 + wave * 32 + mt * 16 + g * 4 + r;
                out[(long)m * DIM + n] = acc[mt][nt][r] + bv;
            }
        }
    }
}

// ---------------------------------------------------------------------------
// MFMA flash attention v9: key-split waves (v8 structure) with two fixes:
// (1) NO runtime indexing into the o[][] register array -- the v8 epilogue's
//     o[dto][qt] forced the whole accumulator into scratch (WRITE_SIZE 139MB,
//     MfmaUtil 13%). Now: compile-time-indexed predicated writes + selects.
// (2) P tile stride = 40 halves (80 B): 16B-aligned for ds_read_b128, and
//     row*20 words mod 32 cycles 8 distinct bank positions -> conflict-free
//     (v8's 32-half rows gave 8-way conflicts, 15.7M cycles).
// Wave-private K 4K | V 4K | P 5K; barrier-free main loop (vmcnt(0) only).
// Fixed-shift softmax C0=4 -> linear j-partials; epilogue = 1 LDS exchange.
// ---------------------------------------------------------------------------
__global__ __launch_bounds__(256, 3) void attn_mfma(
    const unsigned short* __restrict__ qb, const unsigned short* __restrict__ kb,
    const unsigned short* __restrict__ vtb, const unsigned int* __restrict__ mbits,
    unsigned short* __restrict__ zz) {
    const int qblk = blockIdx.x;            // 0..31 (64-query tiles)
    const int h    = blockIdx.y;
    const int bb   = blockIdx.z;
    const int bh   = bb * HEADS + h;
    const int wave = threadIdx.x >> 6;      // key-split: wave w -> keys w*512..
    const int lane = threadIdx.x & 63;
    const int l16  = lane & 15;
    const int g    = lane >> 4;
    const int q0r  = qblk * 64;

    // per wave: K 2048 halves | V 2048 | P 2560 (stride-40 rows) = 13312 B
    __shared__ __align__(16) unsigned short SMEM[4][6656];
    __shared__ float Zs[4][4][16];

    unsigned short* myK = &SMEM[wave][0];
    unsigned short* myV = &SMEM[wave][2048];
    unsigned short* myP = &SMEM[wave][4096];

    const int sw8 = l16 & 7;                // K read swizzle (8 chunks/row)
    const int swv = (l16 >> 1) & 3;         // V read swizzle (4 chunks/row)
    const int skr = lane >> 3;              // K staging: row within 8
    const int skc = ((lane & 7) ^ skr) * 8; // K staging: swizzled chunk
    const int svr = lane >> 2;              // V staging: row within 16
    const int svc = ((lane & 3) ^ ((svr >> 1) & 3)) * 8;

    // Q B-fragments: all 64 queries, d-halves 0/1
    half8 qf[4][2];
    #pragma unroll
    for (int qt = 0; qt < 4; ++qt) {
        const unsigned short* qp = qb + ((long)bh * SEQ + q0r + qt * 16 + l16) * DH + g * 8;
        qf[qt][0] = *reinterpret_cast<const half8*>(qp);
        qf[qt][1] = *reinterpret_cast<const half8*>(qp + 32);
    }

    f32x4 o[4][4] = {};                     // [d-tile][q-tile]
    float Zq[4] = {0.f, 0.f, 0.f, 0.f};
    const float C0 = 4.0f * LOG2E;

    const unsigned int* mb = mbits + (((long)bb * 32 + qblk) * 64 + wave * 16) * 64 + lane;
    const long kbase = (long)bh * SEQ * DH;
    const long vbase = (long)bh * DH * SEQ;
    const int  jb    = wave * 512;

    for (int it = 0; it < 16; ++it) {
        const int j0 = jb + it * 32;
        const unsigned int bits = mb[it * 64];

        #pragma unroll
        for (int i = 0; i < 4; ++i)
            glds16(kb + kbase + (long)(j0 + i * 8 + skr) * DH + skc, myK + i * 512);
        #pragma unroll
        for (int i = 0; i < 4; ++i)
            glds16(vtb + vbase + (long)(i * 16 + svr) * SEQ + j0 + svc, myV + i * 512);
        __builtin_amdgcn_s_waitcnt(0x0F70);  // vmcnt(0): my glds landed (no barrier)

        // ---- S^T = K Q^T, kt-blocked; exp + mask + pack P (stride 40) ----
        #pragma unroll
        for (int kt = 0; kt < 2; ++kt) {
            const int rb = (kt * 16 + l16) * 64;
            const half8 k0 = *reinterpret_cast<const half8*>(&myK[rb + ((g ^ sw8) * 8)]);
            const half8 k1 = *reinterpret_cast<const half8*>(&myK[rb + (((4 + g) ^ sw8) * 8)]);
            f32x4 st[4];
            #pragma unroll
            for (int qt = 0; qt < 4; ++qt) {
                f32x4 acc = {0.f, 0.f, 0.f, 0.f};
                acc = __builtin_amdgcn_mfma_f32_16x16x32_f16(k0, qf[qt][0], acc, 0, 0, 0);
                acc = __builtin_amdgcn_mfma_f32_16x16x32_f16(k1, qf[qt][1], acc, 0, 0, 0);
                st[qt] = acc;
            }
            #pragma unroll
            for (int qt = 0; qt < 4; ++qt) {
                float pm[4];
                #pragma unroll
                for (int r = 0; r < 4; ++r) {
                    const float p = __builtin_amdgcn_exp2f(fmaf(st[qt][r], LOG2E, -C0));
                    pm[r] = ((bits >> (kt * 16 + qt * 4 + r)) & 1u) ? p : 0.f;
                }
                Zq[qt] += (pm[0] + pm[1]) + (pm[2] + pm[3]);
                uint2 pk2;
                pk2.x = pkrtz(pm[0], pm[1]);
                pk2.y = pkrtz(pm[2], pm[3]);
                *reinterpret_cast<uint2*>(&myP[(qt * 16 + l16) * 40 + kt * 16 + g * 4]) = pk2;
            }
        }

        // ---- O^T += V^T P^T (K=32), all 16 tiles ----
        half8 va[4];
        #pragma unroll
        for (int dt = 0; dt < 4; ++dt)
            va[dt] = *reinterpret_cast<const half8*>(&myV[(dt * 16 + l16) * 32 + ((g ^ swv) * 8)]);
        #pragma unroll
        for (int qt = 0; qt < 4; ++qt) {
            const half8 pbq = *reinterpret_cast<const half8*>(&myP[(qt * 16 + l16) * 40 + g * 8]);
            #pragma unroll
            for (int dt = 0; dt < 4; ++dt)
                o[dt][qt] = __builtin_amdgcn_mfma_f32_16x16x32_f16(va[dt], pbq, o[dt][qt], 0, 0, 0);
        }
    }

    // ---- Z: reduce over g-lanes (keys within wave) ----
    #pragma unroll
    for (int qt = 0; qt < 4; ++qt) {
        Zq[qt] += __shfl_xor(Zq[qt], 16, 64);
        Zq[qt] += __shfl_xor(Zq[qt], 32, 64);
    }

    // ---- select own tiles with COMPILE-TIME register indices ----
    f32x4 own[4];
    #pragma unroll
    for (int dt = 0; dt < 4; ++dt)
        if (dt == wave) {                   // uniform predicate, no scratch
            #pragma unroll
            for (int qt = 0; qt < 4; ++qt) own[qt] = o[dt][qt];
        }

    // ---- exchange partials: wave w keeps d-tile w, ships the other 12 ----
    __syncthreads();
    float* lx = (float*)&SMEM[0][0];        // 48 KB, reused
    #pragma unroll
    for (int dt = 0; dt < 4; ++dt) {
        #pragma unroll
        for (int qt = 0; qt < 4; ++qt) {
            if (dt != wave) {
                const int up = (wave < dt) ? wave : wave - 1;
                *reinterpret_cast<f32x4*>(&lx[((dt * 3 + up) * 4 + qt) * 256 + lane * 4]) = o[dt][qt];
            }
        }
    }
    if (g == 0) {
        #pragma unroll
        for (int qt = 0; qt < 4; ++qt) Zs[wave][qt][l16] = Zq[qt];
    }
    __syncthreads();

    #pragma unroll
    for (int qt = 0; qt < 4; ++qt) {
        const float Zt = Zs[0][qt][l16] + Zs[1][qt][l16] + Zs[2][qt][l16] + Zs[3][qt][l16];
        const float inv = 1.f / (Zt + 1e-30f);
        f32x4 acc = own[qt];
        #pragma unroll
        for (int up = 0; up < 3; ++up) {
            const f32x4 p = *reinterpret_cast<const f32x4*>(
                &lx[((wave * 3 + up) * 4 + qt) * 256 + lane * 4]);
            acc[0] += p[0]; acc[1] += p[1]; acc[2] += p[2]; acc[3] += p[3];
        }
        uint2 pk2;
        pk2.x = pkrtz(acc[0] * inv, acc[1] * inv);
        pk2.y = pkrtz(acc[2] * inv, acc[3] * inv);
        const long addr = ((long)bb * SEQ + q0r + qt * 16 + l16) * DIM + h * DH + wave * 16 + g * 4;
        *reinterpret_cast<uint2*>(&zz[addr]) = pk2;
    }
}

// ---------------------------------------------------------------------------
extern "C" void kernel_launch(void* const* d_in, const int* in_sizes, int n_in,
                              void* d_out, int out_size, void* d_ws, size_t ws_size,
                              hipStream_t stream) {
    const float* x     = (const float*)d_in[0];
    const float* mask  = (const float*)d_in[1];
    const float* W_qkv = (const float*)d_in[2];
    const float* W_out = (const float*)d_in[3];
    const float* b_out = (const float*)d_in[4];
    float* out = (float*)d_out;

    unsigned short* ws = (unsigned short*)d_ws;
    unsigned short* xh  = ws;                  // 4M fp16 (reused as z after gemm1)
    unsigned short* WqT = xh  + 4194304;       // 3M fp16
    unsigned short* WoT = WqT + 3145728;       // 1M fp16
    unsigned short* qbu = WoT + 1048576;       // 4M fp16
    unsigned short* kbu = qbu + 4194304;       // 4M fp16
    unsigned short* vtb = kbu + 4194304;       // 4M fp16
    unsigned int*   mbits = (unsigned int*)(vtb + 4194304);  // 256K uints = 1 MB
    unsigned short* zz  = xh;

    convert_f16<<<4096, 256, 0, stream>>>(x, xh);
    transpose_f16<<<dim3(96, 32), 256, 0, stream>>>(W_qkv, WqT, 1024, 3072);
    transpose_f16<<<dim3(32, 32), 256, 0, stream>>>(W_out, WoT, 1024, 1024);
    pack_maskbits<<<dim3(32, 2), 256, 0, stream>>>(mask, mbits);

    gemm_qkv_f16<<<dim3(24, 32), 256, 0, stream>>>(xh, WqT, qbu, kbu, vtb);

    attn_mfma<<<dim3(SEQ / 64, HEADS, BATCH), 256, 0, stream>>>(qbu, kbu, vtb, mbits, zz);

    gemm_out_f16<<<dim3(16, 32), 256, 0, stream>>>(zz, WoT, b_out, out);
}

// Round 14
// 244.489 us; speedup vs baseline: 1.3191x; 1.1891x over previous
//
#include <hip/hip_runtime.h>
#include <hip/hip_bf16.h>

// x: [2, 2048, 1024] f32; mask: [2, 2048, 2048] f32; W_qkv: [1024, 3072] f32
// W_out: [1024, 1024] f32; b_out: [1024] f32; out: [2, 2048, 1024] f32
#define BATCH 2
#define SEQ   2048
#define DIM   1024
#define HEADS 16
#define DH    64
#define N_QKV 3072
#define M_TOT 4096
#define SCALE 0.125f
#define EPS   1e-10f
#define LOG2E 1.442695041f

typedef __attribute__((ext_vector_type(8))) _Float16 half8;
typedef __attribute__((ext_vector_type(4))) float f32x4;

static __device__ __forceinline__ unsigned short f2h(float f) {
    _Float16 h = (_Float16)f;
    return __builtin_bit_cast(unsigned short, h);
}
static __device__ __forceinline__ unsigned int pkrtz(float a, float b) {
#if defined(__has_builtin) && __has_builtin(__builtin_amdgcn_cvt_pkrtz)
    return __builtin_bit_cast(unsigned int, __builtin_amdgcn_cvt_pkrtz(a, b));
#else
    return (unsigned int)f2h(a) | ((unsigned int)f2h(b) << 16);
#endif
}
static __device__ __forceinline__ void glds16(const void* g, void* l) {
    __builtin_amdgcn_global_load_lds((const __attribute__((address_space(1))) void*)g,
                                     (__attribute__((address_space(3))) void*)l,
                                     16, 0, 0);
}

// ---------------------------------------------------------------------------
// Pre-pass: fp32 -> fp16
// ---------------------------------------------------------------------------
__global__ __launch_bounds__(256) void convert_f16(const float* __restrict__ s,
                                                   unsigned short* __restrict__ h) {
    const int i = blockIdx.x * 256 + threadIdx.x;
    float4 v = reinterpret_cast<const float4*>(s)[i];
    uint2 o;
    o.x = pkrtz(v.x, v.y);
    o.y = pkrtz(v.z, v.w);
    reinterpret_cast<uint2*>(h)[i] = o;
}

// ---------------------------------------------------------------------------
// Pre-pass: W [k][n] fp32 -> WT fp16 [n][k]
// ---------------------------------------------------------------------------
__global__ __launch_bounds__(256) void transpose_f16(const float* __restrict__ src,
                                                     unsigned short* __restrict__ th,
                                                     int rows, int cols) {
    __shared__ float tile[32][33];
    const int c0 = blockIdx.x * 32, r0 = blockIdx.y * 32;
    const int tx = threadIdx.x & 31, ty = threadIdx.x >> 5;
    #pragma unroll
    for (int i = ty; i < 32; i += 8)
        tile[i][tx] = src[(long)(r0 + i) * cols + c0 + tx];
    __syncthreads();
    #pragma unroll
    for (int i = ty; i < 32; i += 8)
        th[(long)(c0 + i) * rows + r0 + tx] = f2h(tile[tx][i]);
}

// ---------------------------------------------------------------------------
// Pre-pass: pack binary mask into per-(16x64)-tile lane bitmasks, S^T layout
// (r11 verified): bit (nt*4+r) of lane L =
//   mask[i0 + (L&15)][j0 + nt*16 + (L>>4)*4 + r] != 0
// ---------------------------------------------------------------------------
__global__ __launch_bounds__(256) void pack_maskbits(const float* __restrict__ mask,
                                                     unsigned short* __restrict__ mbits) {
    const int it = blockIdx.x;
    const int bb = blockIdx.y;
    const int t  = threadIdx.x;
    __shared__ unsigned char flags[16][256];
    const int R0 = it * 16;
    const int tl = t >> 6, ln = t & 63;

    for (int c0 = 0; c0 < SEQ; c0 += 256) {
        #pragma unroll
        for (int rr = 0; rr < 16; ++rr)
            flags[rr][t] = mask[((long)bb * SEQ + R0 + rr) * SEQ + c0 + t] != 0.f;
        __syncthreads();
        unsigned int bits = 0;
        #pragma unroll
        for (int nt = 0; nt < 4; ++nt)
            #pragma unroll
            for (int r = 0; r < 4; ++r)
                bits |= (unsigned int)flags[ln & 15][tl * 64 + nt * 16 + ((ln >> 4) << 2) + r]
                        << (nt * 4 + r);
        mbits[(((long)bb * 128 + it) * 32 + (c0 >> 6) + tl) * 64 + ln] = (unsigned short)bits;
        __syncthreads();
    }
}

// ---------------------------------------------------------------------------
// GEMM 1 v2: plain fp16 MFMA, 64x128 tiles, BK=64, XOR-swizzled LDS.
// Grid 24x64 = 1536 blocks (6/CU queued, ~4 resident) -- r13 showed the
// 128x128/768-block config latency-bound at 15% occupancy; smaller tiles
// give cross-block overlap of the glds drain. Wave w: all 64 m-rows x
// n-quarter w (32 cols): 8 acc tiles, 16 MFMA : 12 ds_read : 6 glds /iter.
// ---------------------------------------------------------------------------
__global__ __launch_bounds__(256, 4) void gemm_qkv_f16(
    const unsigned short* __restrict__ Ahg, const unsigned short* __restrict__ Bhg,
    unsigned short* __restrict__ qb, unsigned short* __restrict__ kb,
    unsigned short* __restrict__ vtb) {
    __shared__ __align__(16) unsigned short As[64 * 64];    // 8 KB
    __shared__ __align__(16) unsigned short Bs[128 * 64];   // 16 KB

    const int n0   = blockIdx.x * 128;
    const int m0   = blockIdx.y * 64;
    const int wave = threadIdx.x >> 6;      // n-quarter
    const int lane = threadIdx.x & 63;
    const int l16  = lane & 15;
    const int g    = lane >> 4;
    const int sw   = l16 & 7;

    const int sr8 = lane >> 3;
    const int scg = (lane & 7) ^ sr8;

    f32x4 acc[4][2] = {};                   // [mt][nt]

    for (int k0 = 0; k0 < DIM; k0 += 64) {
        #pragma unroll
        for (int i = 0; i < 2; ++i) {       // A: 64 rows, wave stages 16
            const int row = wave * 16 + i * 8;
            glds16(Ahg + (long)(m0 + row + sr8) * DIM + k0 + scg * 8, &As[row * 64]);
        }
        #pragma unroll
        for (int i = 0; i < 4; ++i) {       // B: 128 rows, wave stages 32
            const int row = wave * 32 + i * 8;
            glds16(Bhg + (long)(n0 + row + sr8) * DIM + k0 + scg * 8, &Bs[row * 64]);
        }
        __syncthreads();

        half8 a[4][2];
        #pragma unroll
        for (int mt = 0; mt < 4; ++mt) {
            const int rbase = (mt * 16 + l16) * 64;
            #pragma unroll
            for (int kc = 0; kc < 2; ++kc)
                a[mt][kc] = *reinterpret_cast<const half8*>(
                    &As[rbase + (((kc * 4 + g) ^ sw) * 8)]);
        }
        #pragma unroll
        for (int nt = 0; nt < 2; ++nt) {
            const int rbase = (wave * 32 + nt * 16 + l16) * 64;
            const half8 b0 = *reinterpret_cast<const half8*>(&Bs[rbase + (((0 + g) ^ sw) * 8)]);
            const half8 b1 = *reinterpret_cast<const half8*>(&Bs[rbase + (((4 + g) ^ sw) * 8)]);
            #pragma unroll
            for (int mt = 0; mt < 4; ++mt) {
                acc[mt][nt] = __builtin_amdgcn_mfma_f32_16x16x32_f16(a[mt][0], b0, acc[mt][nt], 0, 0, 0);
                acc[mt][nt] = __builtin_amdgcn_mfma_f32_16x16x32_f16(a[mt][1], b1, acc[mt][nt], 0, 0, 0);
            }
        }
        __syncthreads();
    }

    #pragma unroll
    for (int nt = 0; nt < 2; ++nt) {
        const int n     = n0 + wave * 32 + nt * 16 + l16;
        const int which = n >> 10;
        const int rem   = n & 1023;
        const int head  = rem >> 6;
        const int d     = rem & 63;
        #pragma unroll
        for (int mt = 0; mt < 4; ++mt) {
            #pragma unroll
            for (int r = 0; r < 4; ++r) {
                const int m  = m0 + mt * 16 + g * 4 + r;
                const int bb = m >> 11;
                const int li = m & 2047;
                const int bh_i = bb * HEADS + head;
                const float val = acc[mt][nt][r];
                if (which == 0)
                    qb[((long)bh_i * SEQ + li) * DH + d] = f2h(val * SCALE);
                else if (which == 1)
                    kb[((long)bh_i * SEQ + li) * DH + d] = f2h(val);
                else
                    vtb[((long)bh_i * DH + d) * SEQ + li] = f2h(val);
            }
        }
    }
}

// ---------------------------------------------------------------------------
// GEMM 2 v2: plain fp16 MFMA, 64x64 tiles, BK=64, XOR-swizzled LDS.
// Grid 16x64 = 1024 blocks = 4/CU (was 2). Wave: 32m x 32n, 8 MFMA : 8 ds.
// ---------------------------------------------------------------------------
__global__ __launch_bounds__(256, 4) void gemm_out_f16(
    const unsigned short* __restrict__ Ahg, const unsigned short* __restrict__ Bhg,
    const float* __restrict__ bias, float* __restrict__ out) {
    __shared__ __align__(16) unsigned short As[64 * 64];
    __shared__ __align__(16) unsigned short Bs[64 * 64];

    const int n0   = blockIdx.x * 64;
    const int m0   = blockIdx.y * 64;
    const int wave = threadIdx.x >> 6;
    const int lane = threadIdx.x & 63;
    const int l16  = lane & 15;
    const int g    = lane >> 4;
    const int wm   = wave & 1;
    const int wn   = wave >> 1;
    const int sw   = l16 & 7;

    const int sr8 = lane >> 3;
    const int scg = (lane & 7) ^ sr8;

    f32x4 acc[2][2] = {};

    for (int k0 = 0; k0 < DIM; k0 += 64) {
        #pragma unroll
        for (int i = 0; i < 2; ++i) {
            const int row = wave * 16 + i * 8;
            glds16(Ahg + (long)(m0 + row + sr8) * DIM + k0 + scg * 8, &As[row * 64]);
            glds16(Bhg + (long)(n0 + row + sr8) * DIM + k0 + scg * 8, &Bs[row * 64]);
        }
        __syncthreads();

        half8 a[2][2];
        #pragma unroll
        for (int mt = 0; mt < 2; ++mt) {
            const int rbase = (wm * 32 + mt * 16 + l16) * 64;
            #pragma unroll
            for (int kc = 0; kc < 2; ++kc)
                a[mt][kc] = *reinterpret_cast<const half8*>(
                    &As[rbase + (((kc * 4 + g) ^ sw) * 8)]);
        }
        #pragma unroll
        for (int nt = 0; nt < 2; ++nt) {
            const int rbase = (wn * 32 + nt * 16 + l16) * 64;
            const half8 b0 = *reinterpret_cast<const half8*>(&Bs[rbase + (((0 + g) ^ sw) * 8)]);
            const half8 b1 = *reinterpret_cast<const half8*>(&Bs[rbase + (((4 + g) ^ sw) * 8)]);
            #pragma unroll
            for (int mt = 0; mt < 2; ++mt) {
                acc[mt][nt] = __builtin_amdgcn_mfma_f32_16x16x32_f16(a[mt][0], b0, acc[mt][nt], 0, 0, 0);
                acc[mt][nt] = __builtin_amdgcn_mfma_f32_16x16x32_f16(a[mt][1], b1, acc[mt][nt], 0, 0, 0);
            }
        }
        __syncthreads();
    }

    #pragma unroll
    for (int nt = 0; nt < 2; ++nt) {
        const int n  = n0 + wn * 32 + nt * 16 + l16;
        const float bv = bias[n];
        #pragma unroll
        for (int mt = 0; mt < 2; ++mt) {
            #pragma unroll
            for (int r = 0; r < 4; ++r) {
                const int m = m0 + wm * 32 + mt * 16 + g * 4 + r;
                out[(long)m * DIM + n] = acc[mt][nt][r] + bv;
            }
        }
    }
}

// ---------------------------------------------------------------------------
// MFMA flash attention v7 (r11 verified, 70 us): all-fp16 fragments, S^T
// orientation, fixed-shift softmax C0=4, j-split x2 in-block (linear
// partials), P packed via cvt_pkrtz, Zpm via ones-row MFMA. LDS 48 KB.
// ---------------------------------------------------------------------------
__global__ __launch_bounds__(512, 6) void attn_mfma(const unsigned short* __restrict__ qb,
                                                    const unsigned short* __restrict__ kb,
                                                    const unsigned short* __restrict__ vtb,
                                                    const unsigned short* __restrict__ mbits,
                                                    unsigned short* __restrict__ zh) {
    const int qt   = blockIdx.x;
    const int h    = blockIdx.y;
    const int bb   = blockIdx.z;
    const int bh   = bb * HEADS + h;
    const int wave = threadIdx.x >> 6;
    const int lane = threadIdx.x & 63;
    const int l16  = lane & 15;
    const int g    = lane >> 4;
    const int wm   = wave >> 1;             // row group 0..3
    const int wj   = wave & 1;              // j half

    const int myrow0 = qt * 64 + wm * 16;

    __shared__ __align__(16) unsigned short KV[2][2][64 * 64];  // [wj][K/V]
    __shared__ __align__(16) unsigned short Ps[8][16 * 64];

    const int sr8 = lane >> 3;
    const int scg = (lane & 7) ^ sr8;
    const int sw  = l16 & 7;

    const unsigned short* qptr = qb + ((long)bh * SEQ + myrow0 + l16) * DH + g * 8;
    const half8 q0 = *reinterpret_cast<const half8*>(qptr);
    const half8 q1 = *reinterpret_cast<const half8*>(qptr + 32);

    half8 ones;
    #pragma unroll
    for (int j = 0; j < 8; ++j) ones[j] = (_Float16)1.0f;

    f32x4 o[4] = {};
    f32x4 oz = {0.f, 0.f, 0.f, 0.f};         // Zpm via ones-row MFMA
    const float C0 = 4.0f * LOG2E;           // fixed shift

    const unsigned short* mb =
        mbits + (((long)bb * 128 + qt * 4 + wm) * 32 + wj * 16) * 64 + lane;
    const long kbase = (long)bh * SEQ * DH;
    const long vbase = (long)bh * DH * SEQ;
    const int  jb    = wj * 1024;

    for (int it = 0; it < 16; ++it) {
        const int j0 = jb + it * 64;
        const unsigned int bits = mb[(long)it * 64];   // independent: issues early

        #pragma unroll
        for (int i = 0; i < 2; ++i) {
            const int row = wm * 16 + i * 8;           // wave-uniform
            glds16(kb  + kbase + (long)(j0 + row + sr8) * DH + scg * 8, &KV[wj][0][row * 64]);
            glds16(vtb + vbase + (long)(row + sr8) * SEQ + j0 + scg * 8, &KV[wj][1][row * 64]);
        }
        __syncthreads();

        // ---- S^T = K Q^T : rows = keys, cols = queries ----
        f32x4 st[4];
        #pragma unroll
        for (int nt = 0; nt < 4; ++nt) {
            const int rbase = (nt * 16 + l16) * 64;
            const half8 k0 = *reinterpret_cast<const half8*>(&KV[wj][0][rbase + ((0 + g) ^ sw) * 8]);
            const half8 k1 = *reinterpret_cast<const half8*>(&KV[wj][0][rbase + (((4 + g) ^ sw) * 8)]);
            f32x4 acc = {0.f, 0.f, 0.f, 0.f};
            acc = __builtin_amdgcn_mfma_f32_16x16x32_f16(k0, q0, acc, 0, 0, 0);
            acc = __builtin_amdgcn_mfma_f32_16x16x32_f16(k1, q1, acc, 0, 0, 0);
            st[nt] = acc;
        }

        // ---- p = exp2(s*log2e - C0), bit-mask, pack 2xfp16 via cvt_pkrtz ----
        #pragma unroll
        for (int nt = 0; nt < 4; ++nt) {
            float pm[4];
            #pragma unroll
            for (int r = 0; r < 4; ++r) {
                const float p = __builtin_amdgcn_exp2f(fmaf(st[nt][r], LOG2E, -C0));
                pm[r] = ((bits >> (nt * 4 + r)) & 1u) ? p : 0.f;
            }
            uint2 pk;
            pk.x = pkrtz(pm[0], pm[1]);
            pk.y = pkrtz(pm[2], pm[3]);
            *reinterpret_cast<uint2*>(
                &Ps[wave][l16 * 64 + (((2 * nt + (g >> 1)) ^ sw) * 8) + (g & 1) * 4]) = pk;
        }

        // ---- O^T += V^T P^T ; Zpm row via ones-MFMA (all lanes get Z) ----
        const half8 pb0 = *reinterpret_cast<const half8*>(&Ps[wave][l16 * 64 + ((0 + g) ^ sw) * 8]);
        const half8 pb1 = *reinterpret_cast<const half8*>(&Ps[wave][l16 * 64 + (((4 + g) ^ sw) * 8)]);
        #pragma unroll
        for (int dt = 0; dt < 4; ++dt) {
            const int vb = (dt * 16 + l16) * 64;
            const half8 v0 = *reinterpret_cast<const half8*>(&KV[wj][1][vb + ((0 + g) ^ sw) * 8]);
            const half8 v1 = *reinterpret_cast<const half8*>(&KV[wj][1][vb + (((4 + g) ^ sw) * 8)]);
            o[dt] = __builtin_amdgcn_mfma_f32_16x16x32_f16(v0, pb0, o[dt], 0, 0, 0);
            o[dt] = __builtin_amdgcn_mfma_f32_16x16x32_f16(v1, pb1, o[dt], 0, 0, 0);
        }
        oz = __builtin_amdgcn_mfma_f32_16x16x32_f16(ones, pb0, oz, 0, 0, 0);
        oz = __builtin_amdgcn_mfma_f32_16x16x32_f16(ones, pb1, oz, 0, 0, 0);
        __syncthreads();
    }

    // ---- combine the two j-halves (linear: fixed shift, no rescale) ----
    float* cmb = (float*)&KV[0][0][0];      // 32 KB free after last barrier
    const int ci = wm * 16 + l16;
    if (wj == 1) {
        #pragma unroll
        for (int dt = 0; dt < 4; ++dt)
            *reinterpret_cast<f32x4*>(&cmb[ci * 68 + dt * 16 + g * 4]) = o[dt];
        if (g == 0) cmb[4352 + ci] = oz[0];
    }
    __syncthreads();
    if (wj == 0) {
        const float Z   = oz[0] + cmb[4352 + ci];
        const float inv = 1.f / (Z + 1e-30f);
        const long obase = ((long)bb * SEQ + myrow0 + l16) * DIM + h * DH;
        #pragma unroll
        for (int dt = 0; dt < 4; ++dt) {
            const f32x4 oc = *reinterpret_cast<const f32x4*>(&cmb[ci * 68 + dt * 16 + g * 4]);
            uint2 pk;
            pk.x = pkrtz((o[dt][0] + oc[0]) * inv, (o[dt][1] + oc[1]) * inv);
            pk.y = pkrtz((o[dt][2] + oc[2]) * inv, (o[dt][3] + oc[3]) * inv);
            *reinterpret_cast<uint2*>(zh + obase + dt * 16 + g * 4) = pk;
        }
    }
}

// ---------------------------------------------------------------------------
extern "C" void kernel_launch(void* const* d_in, const int* in_sizes, int n_in,
                              void* d_out, int out_size, void* d_ws, size_t ws_size,
                              hipStream_t stream) {
    const float* x     = (const float*)d_in[0];
    const float* mask  = (const float*)d_in[1];
    const float* W_qkv = (const float*)d_in[2];
    const float* W_out = (const float*)d_in[3];
    const float* b_out = (const float*)d_in[4];
    float* out = (float*)d_out;

    unsigned short* ws = (unsigned short*)d_ws;
    unsigned short* xh    = ws;                  // 4M fp16 (reused as z after gemm1)
    unsigned short* WqT   = xh    + 4194304;     // 3M fp16
    unsigned short* WoT   = WqT   + 3145728;     // 1M fp16
    unsigned short* qbu   = WoT   + 1048576;     // 4M fp16
    unsigned short* kbu   = qbu   + 4194304;     // 4M fp16
    unsigned short* vtb   = kbu   + 4194304;     // 4M fp16
    unsigned short* mbits = vtb   + 4194304;     // 0.5M -> 41 MB total
    unsigned short* zz    = xh;

    convert_f16<<<4096, 256, 0, stream>>>(x, xh);
    transpose_f16<<<dim3(96, 32), 256, 0, stream>>>(W_qkv, WqT, 1024, 3072);
    transpose_f16<<<dim3(32, 32), 256, 0, stream>>>(W_out, WoT, 1024, 1024);
    pack_maskbits<<<dim3(128, 2), 256, 0, stream>>>(mask, mbits);

    gemm_qkv_f16<<<dim3(24, 64), 256, 0, stream>>>(xh, WqT, qbu, kbu, vtb);

    attn_mfma<<<dim3(SEQ / 64, HEADS, BATCH), 512, 0, stream>>>(qbu, kbu, vtb, mbits, zz);

    gemm_out_f16<<<dim3(16, 64), 256, 0, stream>>>(zz, WoT, b_out, out);
}